// Round 1
// baseline (3326.756 us; speedup 1.0000x reference)
//
#include <hip/hip_runtime.h>
#include <cstdint>
#include <cstddef>

#define TSTEPS 100
#define NB 256
#define INF 2312
#define HIDN 512
#define NOUT 10

// ws layout (float offsets)
#define OFF_POS 0            // 131072 floats
#define OFF_V   131072       // 2560
#define OFF_I   133632       // 2560
#define OFF_Z   136192       // 4096 u64 (two 2048-u64 buffers) = 8192 floats
#define OFF_WT  144384       // 262144 (w_rec transposed)
#define OFF_CI  406528       // 13107200 (input-projection cache)
#define WS_FLOATS 13513728

// init: zero state + build w_recT[h'][h] = w_rec[h][h']
__global__ __launch_bounds__(256) void init_kernel(float* __restrict__ ws,
                                                   const float* __restrict__ w_rec) {
    int n = blockIdx.x * 256 + threadIdx.x;
    if (n < OFF_WT) {
        ws[n] = 0.0f;
    } else if (n < OFF_CI) {
        int m = n - OFF_WT;          // m = hprime*512 + h
        int r = m >> 9, cc = m & 511;
        ws[n] = w_rec[cc * 512 + r];
    }
}

// C[r][h] = sum_k X[r][k] * Win[h][k], fp64 accumulate, fp32 store.
// M=25600, N=512, K=2312. 64x64 tile, 256 threads, 4x4 micro-tile.
__global__ __launch_bounds__(256) void gemm_in(const float* __restrict__ X,
                                               const float* __restrict__ Win,
                                               float* __restrict__ C) {
    __shared__ float As[32][68];   // [k][row], padded
    __shared__ float Bs[32][68];
    const int tid = threadIdx.x;
    const int ty = tid >> 4, tx = tid & 15;
    const int row0 = blockIdx.y * 64, col0 = blockIdx.x * 64;
    const int lr = tid >> 2;            // 0..63
    const int lc = (tid & 3) * 8;       // 0,8,16,24
    double acc[4][4] = {};
    for (int k0 = 0; k0 < INF; k0 += 32) {
        __syncthreads();
#pragma unroll
        for (int q = 0; q < 2; ++q) {
            int kc = lc + q * 4;
            int gk = k0 + kc;
            float4 va, vb;
            if (gk < INF) {   // INF%4==0 and gk%4==0 -> fully in-bounds
                va = *(const float4*)(X + (size_t)(row0 + lr) * INF + gk);
                vb = *(const float4*)(Win + (size_t)(col0 + lr) * INF + gk);
            } else {
                va = make_float4(0.f, 0.f, 0.f, 0.f);
                vb = va;
            }
            As[kc + 0][lr] = va.x; As[kc + 1][lr] = va.y;
            As[kc + 2][lr] = va.z; As[kc + 3][lr] = va.w;
            Bs[kc + 0][lr] = vb.x; Bs[kc + 1][lr] = vb.y;
            Bs[kc + 2][lr] = vb.z; Bs[kc + 3][lr] = vb.w;
        }
        __syncthreads();
#pragma unroll 8
        for (int kk = 0; kk < 32; ++kk) {
            float4 a4 = *(const float4*)&As[kk][ty * 4];
            float4 b4 = *(const float4*)&Bs[kk][tx * 4];
            double ad[4] = {(double)a4.x, (double)a4.y, (double)a4.z, (double)a4.w};
            double bd[4] = {(double)b4.x, (double)b4.y, (double)b4.z, (double)b4.w};
#pragma unroll
            for (int i = 0; i < 4; ++i)
#pragma unroll
                for (int j = 0; j < 4; ++j)
                    acc[i][j] += ad[i] * bd[j];
        }
    }
#pragma unroll
    for (int i = 0; i < 4; ++i) {
        float4 o;
        o.x = (float)acc[i][0]; o.y = (float)acc[i][1];
        o.z = (float)acc[i][2]; o.w = (float)acc[i][3];
        *(float4*)(C + (size_t)(row0 + ty * 4 + i) * HIDN + col0 + tx * 4) = o;
    }
}

// One timestep. grid=256: block = (batch-group 0..31) x (h-chunk 0..7).
// 512 threads: wave = one batch (8 batches/block), lane = h within chunk.
// t in [0,100]: t<100 does recurrence+spike for step t; t>0 does LI readout for step t-1.
__global__ __launch_bounds__(512) void step_kernel(const float* __restrict__ cur_in,
        const float* __restrict__ wT, const float* __restrict__ w_out,
        float* __restrict__ pos, float* __restrict__ v, float* __restrict__ isyn,
        unsigned long long* __restrict__ zbuf, float* __restrict__ out, int t) {
    __shared__ float wslice[192 * 64];   // 48 KB: rows of w_recT slice, 3 passes
    const int tid = threadIdx.x;
    const int wv = tid >> 6, lane = tid & 63;
    const int grp = (int)blockIdx.x >> 3, c = (int)blockIdx.x & 7;
    const int b = grp * 8 + wv;
    const unsigned long long* zprev = zbuf + ((t & 1) ? 2048 : 0);
    unsigned long long* znext = zbuf + ((t & 1) ? 0 : 2048);

    unsigned long long zm[8];
#pragma unroll
    for (int c2 = 0; c2 < 8; ++c2) zm[c2] = zprev[b * 8 + c2];

    if (t < TSTEPS) {
        double acc = 0.0;
        for (int pass = 0; pass < 3; ++pass) {
            const int r0 = pass * 192;
            const int nr = (pass == 2) ? 128 : 192;
            __syncthreads();
            for (int r = wv; r < nr; r += 8)
                wslice[r * 64 + lane] = wT[(size_t)(r0 + r) * HIDN + c * 64 + lane];
            __syncthreads();
            const int w0 = r0 >> 6, w1 = (r0 + nr) >> 6;
            for (int c2 = w0; c2 < w1; ++c2) {
                unsigned int mlo = (unsigned int)(zm[c2] & 0xffffffffull);
                unsigned int mhi = (unsigned int)(zm[c2] >> 32);
                mlo = __builtin_amdgcn_readfirstlane(mlo);
                mhi = __builtin_amdgcn_readfirstlane(mhi);
                float f = 0.0f;
                const int base = (c2 * 64 - r0) * 64 + lane;
                while (mlo) {
                    int bit = __builtin_ctz(mlo); mlo &= mlo - 1;
                    f += wslice[base + bit * 64];
                }
                while (mhi) {
                    int bit = __builtin_ctz(mhi); mhi &= mhi - 1;
                    f += wslice[base + (bit + 32) * 64];
                }
                acc += (double)f;   // per-64-word fp32 partial -> fp64 combine
            }
        }
        const int h = c * 64 + lane;
        float rec32 = (float)acc;
        float ci = cur_in[(size_t)t * (NB * HIDN) + b * HIDN + h];
        float cur = __fadd_rn(__fadd_rn(ci, rec32), 1e-4f);           // (in + rec) + I_APP
        float p = pos[b * HIDN + h];
        float mc = __fmul_rn(2.5e5f, cur);                            // MU*cur
        float dp = __fmul_rn(1e-10f, mc);                             // DT*(...)
        p = __fadd_rn(p, dp);
        float s = __fsub_rn(p, 2.5e-8f);                              // pos - W2
        bool zbit = s > 0.0f;
        p = zbit ? 0.0f : p;                                          // pos*(1-z)
        pos[b * HIDN + h] = p;
        unsigned long long bal = __ballot(zbit ? 1 : 0);
        if (lane == 0) znext[b * 8 + c] = bal;
    }

    if (t > 0) {
        // LI readout for step (t-1), spikes = zm. chunk c handles o=c (+ o=8+c if c<2).
#pragma unroll
        for (int oo = 0; oo < 2; ++oo) {
            int o = (oo == 0) ? c : (c < 2 ? 8 + c : -1);
            if (o < 0) continue;
            double part = 0.0;
#pragma unroll
            for (int c2 = 0; c2 < 8; ++c2) {
                if ((zm[c2] >> lane) & 1ull)
                    part += (double)w_out[o * HIDN + c2 * 64 + lane];
            }
#pragma unroll
            for (int off = 32; off > 0; off >>= 1) part += __shfl_down(part, off);
            if (lane == 0) {
                float inp = (float)part;                              // z @ w_out.T, rounded
                int vi = b * NOUT + o;
                float vv = v[vi], ii = isyn[vi];
                float vn = __fadd_rn(vv, __fmul_rn(1e-8f, __fsub_rn(ii, vv)));
                float t2 = __fmul_rn(2e-8f, ii);
                float in2 = __fadd_rn(__fsub_rn(ii, t2), inp);
                v[vi] = vn; isyn[vi] = in2;
                out[(size_t)(t - 1) * (NB * NOUT) + vi] = vn;
            }
        }
    }
}

extern "C" void kernel_launch(void* const* d_in, const int* in_sizes, int n_in,
                              void* d_out, int out_size, void* d_ws, size_t ws_size,
                              hipStream_t stream) {
    (void)in_sizes; (void)n_in; (void)out_size;
    const float* x     = (const float*)d_in[0];
    const float* w_in  = (const float*)d_in[1];
    const float* w_rec = (const float*)d_in[2];
    const float* w_out = (const float*)d_in[3];
    float* out = (float*)d_out;
    float* ws  = (float*)d_ws;
    if (ws_size < (size_t)WS_FLOATS * 4) return;   // need ~54.1 MB scratch

    float* pos = ws + OFF_POS;
    float* v   = ws + OFF_V;
    float* isn = ws + OFF_I;
    unsigned long long* zbuf = (unsigned long long*)(ws + OFF_Z);
    float* wT = ws + OFF_WT;
    float* ci = ws + OFF_CI;

    hipLaunchKernelGGL(init_kernel, dim3((OFF_CI + 255) / 256), dim3(256), 0, stream,
                       ws, w_rec);
    hipLaunchKernelGGL(gemm_in, dim3(8, 400), dim3(256), 0, stream, x, w_in, ci);
    for (int t = 0; t <= TSTEPS; ++t)
        hipLaunchKernelGGL(step_kernel, dim3(256), dim3(512), 0, stream,
                           ci, wT, w_out, pos, v, isn, zbuf, out, t);
}